// Round 1
// baseline (1231.355 us; speedup 1.0000x reference)
//
#include <hip/hip_runtime.h>
#include <math.h>

// Problem constants (reference: N=16384, D=8, S=8192, diag fill 5.0)
#define NFULL 16384
#define SN 8192
#define DIM 8
#define DIAG_FILL 5.0f

// Workspace layout (bytes):
//   [0,4)            acc (float, zeroed by memset)
//   [256, 256+64K)   hist[16384] (zeroed by memset)
//   [65792, +64K)    offs[16384]
//   [131328, +32K)   csort[8192]
//   [164096, +32K)   sqg[8192]
//   [196864, +256K)  zg[8192*8]   (16B-aligned: 196864 % 16 == 0)
#define OFF_ACC   0
#define OFF_HIST  256
#define OFF_OFFS  (OFF_HIST + NFULL * 4)
#define OFF_CSORT (OFF_OFFS + NFULL * 4)
#define OFF_SQG   (OFF_CSORT + SN * 4)
#define OFF_ZG    (OFF_SQG + SN * 4)

__global__ void hist_kernel(const int* __restrict__ sample_idx, int* __restrict__ hist) {
    int t = blockIdx.x * 256 + threadIdx.x;   // 0..8191
    atomicAdd(&hist[sample_idx[t]], 1);
}

// Exclusive scan of hist[16384] -> offs[16384]. One block, 1024 threads, 16 bins each.
__global__ void scan_kernel(const int* __restrict__ hist, int* __restrict__ offs) {
    __shared__ int tot[1024];
    int t = threadIdx.x;
    int base = t * 16;
    int loc[16];
    int s = 0;
    #pragma unroll
    for (int k = 0; k < 16; k++) { loc[k] = s; s += hist[base + k]; }
    int val = s;
    tot[t] = val;
    __syncthreads();
    for (int off = 1; off < 1024; off <<= 1) {
        int add = (t >= off) ? tot[t - off] : 0;
        __syncthreads();
        val += add;
        tot[t] = val;
        __syncthreads();
    }
    int excl = val - s;   // exclusive prefix over chunks
    #pragma unroll
    for (int k = 0; k < 16; k++) offs[base + k] = excl + loc[k];
}

// csort: sorted sample_idx values (counting-sort emit). One thread per bin.
__global__ void scatter_kernel(const int* __restrict__ hist, const int* __restrict__ offs,
                               int* __restrict__ csort) {
    int b = blockIdx.x * 256 + threadIdx.x;   // 0..16383
    int st = offs[b], cnt = hist[b];
    for (int k = 0; k < cnt; k++) csort[st + k] = b;
}

// Gather z rows (in sorted order) + row squared norms.
__global__ void gatherz_kernel(const float* __restrict__ latent_z, const int* __restrict__ csort,
                               float* __restrict__ zg, float* __restrict__ sqg) {
    int a = blockIdx.x * 256 + threadIdx.x;   // 0..8191
    int r = csort[a];
    const float4* src = (const float4*)(latent_z + (size_t)r * DIM);
    float4 u = src[0], v = src[1];
    float4* dst = (float4*)(zg + (size_t)a * DIM);
    dst[0] = u; dst[1] = v;
    sqg[a] = u.x*u.x + u.y*u.y + u.z*u.z + u.w*u.w
           + v.x*v.x + v.y*v.y + v.z*v.z + v.w*v.w;
}

// Main: 2048 blocks x 256 threads. Block = (j-group of 256 sorted columns) x (i-chunk of 128 rows).
// Lane owns one j (z_j, c_j in registers); loop over rows: wave-uniform z_i load + windowed
// rel gather (sorted columns -> each relation row streamed sequentially, disjoint per j-group).
__global__ __launch_bounds__(256) void
main_kernel(const float* __restrict__ relation, const int* __restrict__ csort,
            const float* __restrict__ zg, const float* __restrict__ sqg,
            float* __restrict__ acc) {
    int jg = blockIdx.x & 31;    // 32 j-groups of 256 columns
    int ic = blockIdx.x >> 5;    // 64 i-chunks of 128 rows
    int t = threadIdx.x;
    int j = jg * 256 + t;

    int cj = csort[j];
    const float4* zj4 = (const float4*)(zg + (size_t)j * DIM);
    float4 p = zj4[0], q = zj4[1];
    float sqj = sqg[j];

    float sum = 0.f;
    int a0 = ic * 128;
    #pragma unroll 4
    for (int k = 0; k < 128; k++) {
        int a = a0 + k;
        int r = csort[a];                       // wave-uniform
        const float4* za4 = (const float4*)(zg + (size_t)a * DIM);
        float4 u = za4[0], v = za4[1];
        float sqa = sqg[a];
        float rel = relation[((size_t)r << 14) + cj];   // windowed gather (sorted cols)
        float dot = u.x*p.x + u.y*p.y + u.z*p.z + u.w*p.w
                  + v.x*q.x + v.y*q.y + v.z*q.z + v.w*q.w;
        float d2 = fmaxf(sqa + sqj - 2.f * dot, 0.f);
        float dist = sqrtf(d2);
        float den = rel;
        if (a == j) { dist = 0.f; den = DIAG_FILL; }    // sorted diagonal == original diagonal
        float d = dist - rel;
        sum += d * d * __builtin_amdgcn_rcpf(den);
    }

    // Reduce 256 threads -> 1 atomicAdd
    #pragma unroll
    for (int o = 32; o > 0; o >>= 1) sum += __shfl_down(sum, o, 64);
    __shared__ float part[4];
    int lane = t & 63, w = t >> 6;
    if (lane == 0) part[w] = sum;
    __syncthreads();
    if (t == 0) atomicAdd(acc, part[0] + part[1] + part[2] + part[3]);
}

__global__ void final_kernel(const float* __restrict__ acc, float* __restrict__ out) {
    out[0] = sqrtf(acc[0]);
}

extern "C" void kernel_launch(void* const* d_in, const int* in_sizes, int n_in,
                              void* d_out, int out_size, void* d_ws, size_t ws_size,
                              hipStream_t stream) {
    const float* latent_z  = (const float*)d_in[0];   // [16384, 8]
    const float* relation  = (const float*)d_in[1];   // [16384, 16384]
    const int*   sample_idx = (const int*)d_in[2];    // [8192]
    float* out = (float*)d_out;

    char* ws = (char*)d_ws;
    float* acc  = (float*)(ws + OFF_ACC);
    int*  hist  = (int*)(ws + OFF_HIST);
    int*  offs  = (int*)(ws + OFF_OFFS);
    int*  csort = (int*)(ws + OFF_CSORT);
    float* sqg  = (float*)(ws + OFF_SQG);
    float* zg   = (float*)(ws + OFF_ZG);

    // zero acc + hist (ws is poisoned 0xAA before every timed launch)
    hipMemsetAsync(d_ws, 0, OFF_HIST + NFULL * 4, stream);

    hist_kernel<<<SN / 256, 256, 0, stream>>>(sample_idx, hist);
    scan_kernel<<<1, 1024, 0, stream>>>(hist, offs);
    scatter_kernel<<<NFULL / 256, 256, 0, stream>>>(hist, offs, csort);
    gatherz_kernel<<<SN / 256, 256, 0, stream>>>(latent_z, csort, zg, sqg);
    main_kernel<<<2048, 256, 0, stream>>>(relation, csort, zg, sqg, acc);
    final_kernel<<<1, 1, 0, stream>>>(acc, out);
}